// Round 7
// baseline (725.984 us; speedup 1.0000x reference)
//
#include <hip/hip_runtime.h>
#include <math.h>

#define N_NODES 100000
#define N_EDGES 1600000
#define NODE_F  64
#define IN_DIM  160          // 2*64 + 32
#define N_TILES 25000        // N_EDGES / 64
#define ZSTRIDE 168          // bf16 elems per z-row (fallback kernel)
#define EDGE_GRID 1536       // fallback: 6 blocks/CU
#define SPQ_GRID 2048        // sorted PQ edge kernel: 8 blocks/CU
#define PRE_GRID 512
#define PRE_TILES 1563       // ceil(100000/64)
#define SCAN_BLOCKS 391      // ceil(100000/256)
#define E_BLOCKS    6250     // N_EDGES/256

typedef __attribute__((ext_vector_type(8))) short short8;   // 8 bf16 = 4 VGPRs
typedef __attribute__((ext_vector_type(4))) float f32x4;

// round-to-nearest-even f32 -> bf16 bits (scalar; staging only)
static __device__ inline unsigned short f2bf(float f) {
    union { float f; unsigned u; } v; v.f = f;
    unsigned r = v.u + 0x7fffu + ((v.u >> 16) & 1u);
    return (unsigned short)(r >> 16);
}

// RNE-round two f32 and pack their high halves into one dword.
static __device__ inline unsigned pack2(float lo, float hi) {
    union { float f; unsigned u; } a, b; a.f = lo; b.f = hi;
    const unsigned ra = a.u + 0x7fffu + ((a.u >> 16) & 1u);
    const unsigned rb = b.u + 0x7fffu + ((b.u >> 16) & 1u);
    return __builtin_amdgcn_perm(rb, ra, 0x07060302u);
}

// LDS row for edge e (0..63) within a tile: MFMA C row (quad*4+r) of m-tile
// mt then holds edge quad*16 + mt*4 + r, so each quad-lane's (mt,r) walk
// visits 16 CONSECUTIVE sorted edges -> carry-chain atomic merge. (R2-verified)
static __device__ inline int permrow(int e) {
    return ((e >> 2) & 3) * 16 + (e >> 4) * 4 + (e & 3);
}

// ===========================================================================
// Counting sort (cheap form): hist -> 3-level scan -> sequential src fill
// -> single-int2 scatter.
// ===========================================================================
__global__ __launch_bounds__(256) void hist_kernel(
    const int* __restrict__ src, int* __restrict__ hist)
{
    const int e = blockIdx.x * 256 + threadIdx.x;
    if (e < N_EDGES) atomicAdd(&hist[src[e]], 1);
}

__global__ __launch_bounds__(256) void scan1_kernel(
    const int* __restrict__ hist, int* __restrict__ partial)
{
    __shared__ int lds[256];
    const int tid = threadIdx.x;
    const int idx = blockIdx.x * 256 + tid;
    lds[tid] = (idx < N_NODES) ? hist[idx] : 0;
    __syncthreads();
    for (int s = 128; s > 0; s >>= 1) {
        if (tid < s) lds[tid] += lds[tid + s];
        __syncthreads();
    }
    if (tid == 0) partial[blockIdx.x] = lds[0];
}

__global__ __launch_bounds__(512) void scan2_kernel(int* __restrict__ partial)
{
    __shared__ int lds[512];
    const int tid = threadIdx.x;
    const int v = (tid < SCAN_BLOCKS) ? partial[tid] : 0;
    lds[tid] = v;
    __syncthreads();
    for (int off = 1; off < 512; off <<= 1) {
        const int t = (tid >= off) ? lds[tid - off] : 0;
        __syncthreads();
        lds[tid] += t;
        __syncthreads();
    }
    if (tid < SCAN_BLOCKS) partial[tid] = lds[tid] - v;   // exclusive
}

// writes exclusive offsets to BOTH offs[] (read-only downstream) and cursor[]
// (consumed by scatter2's atomic bump).
__global__ __launch_bounds__(256) void scan3_kernel(
    const int* __restrict__ hist, const int* __restrict__ partial,
    int* __restrict__ offs, int* __restrict__ cursor)
{
    __shared__ int lds[256];
    const int tid = threadIdx.x;
    const int idx = blockIdx.x * 256 + tid;
    const int v = (idx < N_NODES) ? hist[idx] : 0;
    lds[tid] = v;
    __syncthreads();
    for (int off = 1; off < 256; off <<= 1) {
        const int t = (tid >= off) ? lds[tid - off] : 0;
        __syncthreads();
        lds[tid] += t;
        __syncthreads();
    }
    if (idx < N_NODES) {
        const int x = lds[tid] - v + partial[blockIdx.x];
        offs[idx]   = x;
        cursor[idx] = x;
    }
}

// sSrc written SEQUENTIALLY per node range (vs R2's random scatter of 3 arrays)
__global__ __launch_bounds__(256) void fill_src_kernel(
    const int* __restrict__ offs, int* __restrict__ sSrc)
{
    const int n = blockIdx.x * 256 + threadIdx.x;
    if (n >= N_NODES) return;
    const int s = offs[n];
    const int e = (n + 1 < N_NODES) ? offs[n + 1] : N_EDGES;
    for (int i = s; i < e; ++i) sSrc[i] = n;
}

__global__ __launch_bounds__(256) void scatter2_kernel(
    const int* __restrict__ src, const int* __restrict__ tgt,
    int* __restrict__ cursor, int2* __restrict__ tp)
{
    const int e = blockIdx.x * 256 + threadIdx.x;
    if (e >= N_EDGES) return;
    const int s = src[e];
    const int pos = atomicAdd(&cursor[s], 1);
    tp[pos] = make_int2(tgt[e], e);    // one 8B store, L2-absorbed
}

// ===========================================================================
// Precompute: PS[n][2f+m] = x_n @ Wm[0:64,f], QT[n][2f+m] = x_n @ Wm[64:128,f]
// (m: 0=W_f, 1=W_s). Verbatim from round 6 (passed).
// ===========================================================================
__global__ __launch_bounds__(256, 3) void precompute_kernel(
    const float* __restrict__ X,
    const float* __restrict__ W_f, const float* __restrict__ W_s,
    float* __restrict__ PS, float* __restrict__ QT)
{
    __shared__ __align__(16) short wtps[128 * 68];
    __shared__ __align__(16) short wtqt[128 * 68];
    __shared__ __align__(16) short xl[64 * 72];
    unsigned* xl32 = (unsigned*)xl;

    const int tid  = threadIdx.x;
    const int wave = tid >> 6;
    const int lane = tid & 63;
    const int quad = lane >> 4;
    const int l15  = lane & 15;

    for (int idx = tid; idx < 128 * 64; idx += 256) {
        const int c = idx >> 6;
        const int k = idx & 63;
        const int j = c >> 1;
        const float* W = (c & 1) ? W_s : W_f;
        wtps[c * 68 + k] = (short)f2bf(W[k * 64 + j]);
        wtqt[c * 68 + k] = (short)f2bf(W[(k + 64) * 64 + j]);
    }
    __syncthreads();

    const short* wt = (wave >> 1) ? wtqt : wtps;
    const int colbase = (wave & 1) * 64;
    float* const OUT = (wave >> 1) ? QT : PS;

    short8 bfr[4][2];
#pragma unroll
    for (int nt = 0; nt < 4; ++nt)
#pragma unroll
        for (int kc = 0; kc < 2; ++kc)
            bfr[nt][kc] = *(const short8*)&wt[(colbase + nt * 16 + l15) * 68 + kc * 32 + quad * 8];

    for (int t = blockIdx.x; t < PRE_TILES; t += PRE_GRID) {
        const int n0 = t * 64;
        __syncthreads();
        for (int idx = tid; idx < 64 * 16; idx += 256) {
            const int row = idx >> 4, c4 = idx & 15;
            float4 v = {0.f, 0.f, 0.f, 0.f};
            if (n0 + row < N_NODES)
                v = *(const float4*)&X[(size_t)(n0 + row) * 64 + c4 * 4];
            uint2 o; o.x = pack2(v.x, v.y); o.y = pack2(v.z, v.w);
            *(uint2*)&xl32[row * 36 + c4 * 2] = o;
        }
        __syncthreads();

#pragma unroll
        for (int mt = 0; mt < 4; ++mt) {
            short8 a0 = *(const short8*)&xl[(mt * 16 + l15) * 72 + 0 * 32 + quad * 8];
            short8 a1 = *(const short8*)&xl[(mt * 16 + l15) * 72 + 1 * 32 + quad * 8];
#pragma unroll
            for (int nt = 0; nt < 4; ++nt) {
                f32x4 acc = {0.f, 0.f, 0.f, 0.f};
                acc = __builtin_amdgcn_mfma_f32_16x16x32_bf16(a0, bfr[nt][0], acc, 0, 0, 0);
                acc = __builtin_amdgcn_mfma_f32_16x16x32_bf16(a1, bfr[nt][1], acc, 0, 0, 0);
#pragma unroll
                for (int r = 0; r < 4; ++r) {
                    const int node = n0 + mt * 16 + quad * 4 + r;
                    if (node < N_NODES)
                        OUT[(size_t)node * 128 + colbase + nt * 16 + l15] = acc[r];
                }
            }
        }
    }
}

// ===========================================================================
// Sorted PQ edge kernel: stage perm-gathered edge_attrs -> K=32 MFMA (edge
// part) -> epilogue gathers QT per edge, PS once per src-run, carry-chain
// merged atomics (runs avg 16 -> ~8x fewer atomic ops than the ~270G/s-
// pinned unsorted variants).
// ===========================================================================
__global__ __launch_bounds__(256, 8) void edge_sorted_pq_kernel(
    const float* __restrict__ PS,
    const float* __restrict__ QT,
    const int*   __restrict__ sSrc,
    const int2*  __restrict__ tp,     // {tgt, perm} per sorted position
    const float* __restrict__ edge_attrs,
    const float* __restrict__ W_f, const float* __restrict__ b_f,
    const float* __restrict__ W_s, const float* __restrict__ b_s,
    float* __restrict__ msg)
{
    __shared__ __align__(16) short ebuf[64 * 40];   // edge tile, 5120 B
    __shared__ __align__(16) short wet[64 * 72];    // W_e^T both matrices, 9216 B

    const int tid  = threadIdx.x;
    const int wave = tid >> 6;
    const int lane = tid & 63;
    const int quad = lane >> 4;
    const int l15  = lane & 15;

    // ---- Stage W edge-part transposed: wet[c][k] (F) / wet[c][32+k] (S).
    for (int idx = tid; idx < 64 * 32; idx += 256) {
        const int c = idx >> 5, k = idx & 31;
        wet[c * 72 + k]      = (short)f2bf(W_f[(k + 128) * 64 + c]);
        wet[c * 72 + 32 + k] = (short)f2bf(W_s[(k + 128) * 64 + c]);
    }
    __syncthreads();
    const short8 bFe = *(const short8*)&wet[(16 * wave + l15) * 72 + quad * 8];
    const short8 bSe = *(const short8*)&wet[(16 * wave + l15) * 72 + 32 + quad * 8];

    const float bias_f = b_f[16 * wave + l15];
    const float bias_s = b_s[16 * wave + l15];
    const int   fcol2  = 2 * (16 * wave + l15);     // float2 offset in PS/QT rows
    float* const msgf  = msg + 16 * wave + l15;

    const int sel = tid >> 2;        // edge within tile (staging)
    const int sg  = tid & 3;         // 8-feature group (staging)

    // Prefetch first tile.
    int  srcv = sSrc[blockIdx.x * 64 + lane];
    int2 tpv  = tp[blockIdx.x * 64 + lane];

    for (int t = blockIdx.x; t < N_TILES; t += SPQ_GRID) {
        __syncthreads();   // protect ebuf from previous iteration's readers

        // ---- Edge attrs (f32 -> bf16), perm-gathered 128B rows, permrow layout.
        {
            const int pe  = __shfl(tpv.y, sel);
            const int row = permrow(sel);
            const float4 v0 = *(const float4*)&edge_attrs[(size_t)pe * 32 + sg * 8];
            const float4 v1 = *(const float4*)&edge_attrs[(size_t)pe * 32 + sg * 8 + 4];
            short8 o;
            unsigned* o32 = (unsigned*)&o;
            o32[0] = pack2(v0.x, v0.y); o32[1] = pack2(v0.z, v0.w);
            o32[2] = pack2(v1.x, v1.y); o32[3] = pack2(v1.z, v1.w);
            *(short8*)&ebuf[row * 40 + sg * 8] = o;
        }

        // Prefetch next tile (overlaps MFMA+epilogue).
        const int tn = t + SPQ_GRID;
        int  nsrc = 0; int2 ntp = make_int2(0, 0);
        if (tn < N_TILES) {
            nsrc = sSrc[tn * 64 + lane];
            ntp  = tp[tn * 64 + lane];
        }
        __syncthreads();

        // ---- 4 m-tiles x K=32 x 2 matrices + carry-chain epilogue.
        int lastn = -1;
        float carry = 0.0f, psx = 0.0f, psy = 0.0f;
#pragma unroll
        for (int mt = 0; mt < 4; ++mt) {
            const short8 a = *(const short8*)&ebuf[(mt * 16 + l15) * 40 + quad * 8];
            f32x4 accF = {0.f, 0.f, 0.f, 0.f};
            f32x4 accS = {0.f, 0.f, 0.f, 0.f};
            accF = __builtin_amdgcn_mfma_f32_16x16x32_bf16(a, bFe, accF, 0, 0, 0);
            accS = __builtin_amdgcn_mfma_f32_16x16x32_bf16(a, bSe, accS, 0, 0, 0);
#pragma unroll
            for (int r = 0; r < 4; ++r) {
                const int e = quad * 16 + mt * 4 + r;   // sorted edge in tile
                const int n = __shfl(srcv, e);          // quad-uniform
                const int g = __shfl(tpv.x, e);
                const float2 qt2 = *(const float2*)&QT[(size_t)g * 128 + fcol2];
                if (n != lastn) {
                    if (lastn >= 0) atomicAdd(&msgf[lastn * 64], carry);
                    const float2 p2 = *(const float2*)&PS[(size_t)n * 128 + fcol2];
                    psx = p2.x; psy = p2.y;
                    lastn = n; carry = 0.0f;
                }
                const float xf = accF[r] + psx + qt2.x + bias_f;
                const float xs = accS[r] + psy + qt2.y + bias_s;
                const float sig = __builtin_amdgcn_rcpf(1.0f + __expf(-xf));
                const float sp  = fmaxf(xs, 0.0f) + __logf(1.0f + __expf(-fabsf(xs)));
                carry += sig * sp;
            }
        }
        atomicAdd(&msgf[lastn * 64], carry);   // flush last run of the tile

        srcv = nsrc;
        tpv  = ntp;
    }
}

// ===========================================================================
// Fallback edge kernel (round-0 form) if workspace too small.
// ===========================================================================
__global__ __launch_bounds__(256, 6) void edge_kernel(
    const float* __restrict__ node_attrs,
    const int*   __restrict__ edge_src,
    const int*   __restrict__ edge_tgt,
    const float* __restrict__ edge_attrs,
    const float* __restrict__ W_f, const float* __restrict__ b_f,
    const float* __restrict__ W_s, const float* __restrict__ b_s,
    float* __restrict__ msg)
{
    __shared__ __align__(16) short sbuf[64 * ZSTRIDE];
    unsigned* sbuf32 = (unsigned*)sbuf;

    const int tid  = threadIdx.x;
    const int wave = tid >> 6;
    const int lane = tid & 63;
    const int quad = lane >> 4;
    const int l15  = lane & 15;

    short8 bF[5], bS[5];
#pragma unroll
    for (int mat = 0; mat < 2; ++mat) {
        const float* W = mat ? W_s : W_f;
        __syncthreads();
        for (int idx = tid; idx < IN_DIM * 64; idx += 256) {
            const int k = idx >> 6, n = idx & 63;
            sbuf[n * ZSTRIDE + k] = (short)f2bf(W[idx]);
        }
        __syncthreads();
#pragma unroll
        for (int kc = 0; kc < 5; ++kc) {
            const short8 b = *(const short8*)&sbuf[(16 * wave + l15) * ZSTRIDE + kc * 32 + quad * 8];
            if (mat) bS[kc] = b; else bF[kc] = b;
        }
    }

    const float bias_f = b_f[16 * wave + l15];
    const float bias_s = b_s[16 * wave + l15];
    float* const msgf  = msg + 16 * wave + l15;

    int srcv = edge_src[blockIdx.x * 64 + lane];
    int tgtv = edge_tgt[blockIdx.x * 64 + lane];

    for (int t = blockIdx.x; t < N_TILES; t += EDGE_GRID) {
        const int e0 = t * 64;
        __syncthreads();
#pragma unroll
        for (int i = 0; i < 8; ++i) {
            const int el   = i * 2 + (quad >> 1);
            const int half = quad & 1;
            const int sl   = 16 * wave + el;
            const int ns   = __shfl(srcv, sl);
            const int nt   = __shfl(tgtv, sl);
            const int node = half ? nt : ns;
            const float4 v = *(const float4*)&node_attrs[node * 64 + l15 * 4];
            uint2 o; o.x = pack2(v.x, v.y); o.y = pack2(v.z, v.w);
            *(uint2*)&sbuf32[sl * (ZSTRIDE / 2) + half * 32 + l15 * 2] = o;
        }
#pragma unroll
        for (int i = 0; i < 2; ++i) {
            const int p  = i * 256 + tid;
            const int el = p >> 3, g = p & 7;
            const float4 v = *(const float4*)&edge_attrs[(size_t)(e0 + el) * 32 + g * 4];
            uint2 o; o.x = pack2(v.x, v.y); o.y = pack2(v.z, v.w);
            *(uint2*)&sbuf32[el * (ZSTRIDE / 2) + 64 + g * 2] = o;
        }
        const int tn = t + EDGE_GRID;
        int nsrc = 0, ntgt = 0;
        if (tn < N_TILES) {
            nsrc = edge_src[tn * 64 + lane];
            ntgt = edge_tgt[tn * 64 + lane];
        }
        __syncthreads();
#pragma unroll
        for (int mt = 0; mt < 4; ++mt) {
            f32x4 accF = {0.f, 0.f, 0.f, 0.f};
            f32x4 accS = {0.f, 0.f, 0.f, 0.f};
#pragma unroll
            for (int kc = 0; kc < 5; ++kc) {
                const short8 a = *(const short8*)&sbuf[(mt * 16 + l15) * ZSTRIDE + kc * 32 + quad * 8];
                accF = __builtin_amdgcn_mfma_f32_16x16x32_bf16(a, bF[kc], accF, 0, 0, 0);
                accS = __builtin_amdgcn_mfma_f32_16x16x32_bf16(a, bS[kc], accS, 0, 0, 0);
            }
#pragma unroll
            for (int r = 0; r < 4; ++r) {
                const float xf = accF[r] + bias_f;
                const float xs = accS[r] + bias_s;
                const float sig = __builtin_amdgcn_rcpf(1.0f + __expf(-xf));
                const float sp  = fmaxf(xs, 0.0f) + __logf(1.0f + __expf(-fabsf(xs)));
                const float h   = sig * sp;
                const int sl    = mt * 16 + quad * 4 + r;
                const int node  = __shfl(srcv, sl);
                atomicAdd(&msgf[node * 64], h);
            }
        }
        srcv = nsrc;
        tgtv = ntgt;
    }
}

// ---------------------------------------------------------------------------
// Phase 2: per-feature sum / sumsq over nodes.
// ---------------------------------------------------------------------------
#define STATS_BLOCKS 400
__global__ __launch_bounds__(256) void stats_kernel(
    const float* __restrict__ msg, float* __restrict__ stats)
{
    const int tid = threadIdx.x;
    const int f = tid & 63;
    const int g = tid >> 6;
    float s = 0.0f, q = 0.0f;
    for (int r = blockIdx.x * 4 + g; r < N_NODES; r += STATS_BLOCKS * 4) {
        const float v = msg[r * 64 + f];
        s += v;
        q = fmaf(v, v, q);
    }
    __shared__ float rs[4][64];
    __shared__ float rq[4][64];
    rs[g][f] = s;
    rq[g][f] = q;
    __syncthreads();
    if (tid < 64) {
        const float ss = rs[0][f] + rs[1][f] + rs[2][f] + rs[3][f];
        const float qq = rq[0][f] + rq[1][f] + rq[2][f] + rq[3][f];
        atomicAdd(&stats[f], ss);
        atomicAdd(&stats[64 + f], qq);
    }
}

// ---------------------------------------------------------------------------
// Phase 3: in-place BN (training stats, biased var) + residual.
// ---------------------------------------------------------------------------
__global__ __launch_bounds__(256) void norm_kernel(
    const float* __restrict__ node_attrs,
    const float* __restrict__ stats,
    const float* __restrict__ gamma,
    const float* __restrict__ beta,
    float* __restrict__ out)
{
    const int i = blockIdx.x * blockDim.x + threadIdx.x;
    const int idx = i * 4;
    if (idx >= N_NODES * 64) return;
    const int f = idx & 63;
    const float inv_n = 1.0f / (float)N_NODES;

    const float4 m4 = *(const float4*)&out[idx];
    const float4 x4 = *(const float4*)&node_attrs[idx];

    float mean[4], rstd[4], gm[4], bt[4];
#pragma unroll
    for (int j = 0; j < 4; ++j) {
        mean[j] = stats[f + j] * inv_n;
        const float var = stats[64 + f + j] * inv_n - mean[j] * mean[j];
        rstd[j] = rsqrtf(var + 1e-5f);
        gm[j] = gamma[f + j];
        bt[j] = beta[f + j];
    }
    float4 o;
    o.x = x4.x + (m4.x - mean[0]) * rstd[0] * gm[0] + bt[0];
    o.y = x4.y + (m4.y - mean[1]) * rstd[1] * gm[1] + bt[1];
    o.z = x4.z + (m4.z - mean[2]) * rstd[2] * gm[2] + bt[2];
    o.w = x4.w + (m4.w - mean[3]) * rstd[3] * gm[3] + bt[3];
    *(float4*)&out[idx] = o;
}

extern "C" void kernel_launch(void* const* d_in, const int* in_sizes, int n_in,
                              void* d_out, int out_size, void* d_ws, size_t ws_size,
                              hipStream_t stream)
{
    const float* node_attrs = (const float*)d_in[0];
    const int*   edge_index = (const int*)d_in[1];   // [2, E] int32
    const float* edge_attrs = (const float*)d_in[2];
    const float* W_f   = (const float*)d_in[3];
    const float* b_f   = (const float*)d_in[4];
    const float* W_s   = (const float*)d_in[5];
    const float* b_s   = (const float*)d_in[6];
    const float* gamma = (const float*)d_in[7];
    const float* beta  = (const float*)d_in[8];

    float* out   = (float*)d_out;          // doubles as the msg accumulator
    float* stats = (float*)d_ws;           // 128 floats at ws+0

    // Workspace layout (bytes):
    //   [0,512)                  stats
    //   [1024,3072)              scan partials (512 ints)
    //   [4096,404096)            hist (100000 ints)
    //   [409600,809604)          offs (100001-ish; offs[n], n<N)
    //   [811008,1211008)         cursor (100000 ints)
    //   [1212416,7612416)        sSrc (1.6M ints)
    //   [8388608,21188608)       tp (1.6M int2)
    //   [25165824, +51.2M)       PS
    //   [76365824, +51.2M)       QT
    char* wsb    = (char*)d_ws;
    int*  partial = (int*)(wsb + 1024);
    int*  hist    = (int*)(wsb + 4096);
    int*  offs    = (int*)(wsb + 409600);
    int*  cursor  = (int*)(wsb + 811008);
    int*  sSrc    = (int*)(wsb + 1212416);
    int2* tp      = (int2*)(wsb + 8388608);
    float* PS     = (float*)(wsb + 25165824);
    float* QT     = PS + (size_t)N_NODES * 128;
    const size_t WS_NEED = 25165824 + 2ull * N_NODES * 128 * sizeof(float); // ~127.6MB

    const int* edge_src = edge_index;
    const int* edge_tgt = edge_index + N_EDGES;

    hipMemsetAsync(out, 0, (size_t)N_NODES * NODE_F * sizeof(float), stream);
    hipMemsetAsync(stats, 0, 512, stream);

    if (ws_size >= WS_NEED) {
        hipMemsetAsync(hist, 0, (size_t)N_NODES * sizeof(int), stream);
        precompute_kernel<<<PRE_GRID, 256, 0, stream>>>(node_attrs, W_f, W_s, PS, QT);
        hist_kernel<<<E_BLOCKS, 256, 0, stream>>>(edge_src, hist);
        scan1_kernel<<<SCAN_BLOCKS, 256, 0, stream>>>(hist, partial);
        scan2_kernel<<<1, 512, 0, stream>>>(partial);
        scan3_kernel<<<SCAN_BLOCKS, 256, 0, stream>>>(hist, partial, offs, cursor);
        fill_src_kernel<<<SCAN_BLOCKS, 256, 0, stream>>>(offs, sSrc);
        scatter2_kernel<<<E_BLOCKS, 256, 0, stream>>>(edge_src, edge_tgt, cursor, tp);
        edge_sorted_pq_kernel<<<SPQ_GRID, 256, 0, stream>>>(
            PS, QT, sSrc, tp, edge_attrs, W_f, b_f, W_s, b_s, out);
    } else {
        edge_kernel<<<EDGE_GRID, 256, 0, stream>>>(
            node_attrs, edge_src, edge_tgt, edge_attrs, W_f, b_f, W_s, b_s, out);
    }

    stats_kernel<<<STATS_BLOCKS, 256, 0, stream>>>(out, stats);

    norm_kernel<<<(N_NODES * NODE_F / 4 + 255) / 256, 256, 0, stream>>>(
        node_attrs, stats, gamma, beta, out);
}